// Round 1
// 676.280 us; speedup vs baseline: 1.0059x; 1.0059x over previous
//
#include <hip/hip_runtime.h>
#include <stdint.h>

typedef _Float16 f16x8 __attribute__((ext_vector_type(8)));
typedef float floatx4 __attribute__((ext_vector_type(4)));

// Split fp32 into f16 hi + f16 lo, lo pre-scaled by 2048 (2^11) so it stays in
// the f16 normal range (MFMA may flush f16 denormals). x ~= hi + lo/2048.
__device__ __forceinline__ void f2h2(float x, unsigned short& hi, unsigned short& lo) {
  _Float16 h = (_Float16)x;
  float r = (x - (float)h) * 2048.0f;
  _Float16 l = (_Float16)r;
  union { _Float16 f; unsigned short u; } a, b;
  a.f = h; b.f = l;
  hi = a.u; lo = b.u;
}

// Async global->LDS 16B copy. LDS dest is wave-uniform base + lane*16 (HW);
// global source is per-lane.
__device__ __forceinline__ void async_copy16(void* lds, const void* gsrc) {
  __builtin_amdgcn_global_load_lds(
      (const __attribute__((address_space(1))) unsigned int*)gsrc,
      (__attribute__((address_space(3))) unsigned int*)lds, 16, 0, 0);
}

// ---------------------------------------------------------------------------
// K0: weight conversion to f16 hi/lo pairs.
//   bt  : NEW fragment-major layout for k1's async staging:
//         btH[((s*8+ct)*64+lane)*8+e] = H(B[n=ct*16+(lane&15)][k=s*32+(lane>>4)*8+e])
//         (s=0..23 K-steps of 32; k<384 -> w_in0, k>=384 -> w_in1)
//   wrt : unchanged [128 n][128 k], 4 mats Wr1[0],Wr2[0],Wr1[1],Wr2[1]
//   angt: unchanged [16 n][128 k] (n>=14 zero-padded)
// ---------------------------------------------------------------------------
__global__ __launch_bounds__(256) void k0_convert(
    const float* __restrict__ w_in0, const float* __restrict__ w_in1,
    const float* __restrict__ Wr1, const float* __restrict__ Wr2,
    const float* __restrict__ w_ang,
    unsigned short* __restrict__ btH, unsigned short* __restrict__ btL,
    unsigned short* __restrict__ wrtH, unsigned short* __restrict__ wrtL,
    unsigned short* __restrict__ angtH, unsigned short* __restrict__ angtL) {
  int e = blockIdx.x * 256 + threadIdx.x;
  if (e < 24 * 4096) {  // 98304: fragment-major bt
    int s = e >> 12, rem = e & 4095;
    int ct = rem >> 9, lane = (rem >> 3) & 63, el = rem & 7;
    int n = ct * 16 + (lane & 15);
    int k = s * 32 + ((lane >> 4) << 3) + el;
    float v = (k < 384) ? w_in0[k * 128 + n] : w_in1[(k - 384) * 128 + n];
    f2h2(v, btH[e], btL[e]);
  }
  if (e < 4 * 128 * 128) {
    int mi = e / 16384, rem = e % 16384;
    int n = rem / 128, k = rem % 128;
    int blk = mi >> 1, which = mi & 1;
    const float* W = which ? Wr2 : Wr1;
    f2h2(W[blk * 16384 + k * 128 + n], wrtH[e], wrtL[e]);
  }
  if (e < 16 * 128) {
    int n = e / 128, k = e % 128;
    float v = (n < 14) ? w_ang[k * 14 + n] : 0.0f;
    f2h2(v, angtH[e], angtL[e]);
  }
}

// ---------------------------------------------------------------------------
// K1: act[N,128] = relu(rep0)@w_in0 + relu(rep1)@w_in1 + (b_in0+b_in1)
// Async double-buffered pipeline:
//   A (fp32 rep tile) and B (f16 hi/lo, fragment-major) staged via
//   global_load_lds 16B; relu+f2h2 of A done at fragment-read time.
//   Raw s_barrier + counted s_waitcnt vmcnt(8) keeps next-step loads in
//   flight across the barrier (T3/T4 minimal template).
// LDS layouts (all linear -> conflict-free b128 reads):
//   Ab[pb]: half h of chunk c at float index h*2048 + c*4, where chunk
//           c=(w*2+rt)*64+lane holds A[row0+w*32+rt*16+(lane&15)]
//                                   [cb+(lane>>4)*8 .. +7] (h=0: k+0..3, h=1: k+4..7)
//   BH/BL[pb]: identity copy of the 8 KB fragment-major step block.
// act output: fragment-native order, per-lane contiguous float4:
//   act[(((blk*4+w)*2+rt)*8+ct)*256 + lane*4 + reg]
// ---------------------------------------------------------------------------
__global__ __launch_bounds__(256) void k1_gemm_in(
    const float* __restrict__ rep0, const float* __restrict__ rep1,
    const float* __restrict__ b_in0, const float* __restrict__ b_in1,
    const unsigned short* __restrict__ btH, const unsigned short* __restrict__ btL,
    float* __restrict__ act) {
  __shared__ float Ab[2][4096];                  // 32 KB
  __shared__ unsigned short BH[2][4096];         // 16 KB
  __shared__ unsigned short BL[2][4096];         // 16 KB
  const int tid = threadIdx.x;
  const int lane = tid & 63, w = tid >> 6;
  const int m = lane & 15;
  const int row0 = blockIdx.x * 128;

  // Per-lane A source offsets (floats, before +cb) and wave-uniform LDS dests.
  // Issue r: rp=r&1 selects rt-group, h=r>>1 selects 4-float half.
  int aoff[4], adst[4];
#pragma unroll
  for (int r = 0; r < 4; ++r) {
    int rp = r & 1, h = r >> 1;
    aoff[r] = (row0 + (w * 2 + rp) * 16 + m) * 384 + ((lane >> 4) << 3) + h * 4;
    adst[r] = h * 2048 + (w * 2 + rp) * 256;
  }
  const int bsrc0 = (w * 2) * 512 + lane * 8;  // shorts; +512 for r=1

  floatx4 acc1[2][8], acc2[2][8];
#pragma unroll
  for (int rt = 0; rt < 2; ++rt)
#pragma unroll
    for (int ct = 0; ct < 8; ++ct) {
      acc1[rt][ct] = (floatx4){0.f, 0.f, 0.f, 0.f};
      acc2[rt][ct] = (floatx4){0.f, 0.f, 0.f, 0.f};
    }

  auto stage = [&](int pb, int s) {
    const float* __restrict__ rep = (s < 12) ? rep0 : rep1;
    const int cb = (s < 12 ? s : s - 12) * 32;
#pragma unroll
    for (int r = 0; r < 4; ++r)
      async_copy16(&Ab[pb][adst[r]], rep + aoff[r] + cb);
#pragma unroll
    for (int r = 0; r < 2; ++r) {
      async_copy16(&BH[pb][(w * 2 + r) * 512], btH + (size_t)s * 4096 + bsrc0 + r * 512);
      async_copy16(&BL[pb][(w * 2 + r) * 512], btL + (size_t)s * 4096 + bsrc0 + r * 512);
    }
  };

  stage(0, 0);
#pragma unroll 2
  for (int s = 0; s < 24; ++s) {
    const int pb = s & 1;
    if (s < 23) {
      stage(pb ^ 1, s + 1);  // issue next step's 8 loads/lane first
      // wait for step-s loads only; the 8 newest (step s+1) stay in flight
      asm volatile("s_waitcnt vmcnt(8)" ::: "memory");
    } else {
      asm volatile("s_waitcnt vmcnt(0)" ::: "memory");
    }
    __builtin_amdgcn_s_barrier();  // all waves' step-s data now in LDS
    asm volatile("" ::: "memory");

    // A fragments: read fp32, relu + hi/lo split in registers.
    f16x8 ah[2], al[2];
#pragma unroll
    for (int rt = 0; rt < 2; ++rt) {
      const float* ap = &Ab[pb][((w * 2 + rt) * 64 + lane) * 4];
      float4 x0 = *reinterpret_cast<const float4*>(ap);
      float4 x1 = *reinterpret_cast<const float4*>(ap + 2048);
      float xs[8] = {x0.x, x0.y, x0.z, x0.w, x1.x, x1.y, x1.z, x1.w};
#pragma unroll
      for (int e = 0; e < 8; ++e) {
        float x = fmaxf(xs[e], 0.f);
        _Float16 hh = (_Float16)x;
        ah[rt][e] = hh;
        al[rt][e] = (_Float16)((x - (float)hh) * 2048.0f);
      }
    }
#pragma unroll
    for (int ct = 0; ct < 8; ++ct) {
      f16x8 bh = *reinterpret_cast<const f16x8*>(&BH[pb][(ct * 64 + lane) * 8]);
      f16x8 bl = *reinterpret_cast<const f16x8*>(&BL[pb][(ct * 64 + lane) * 8]);
#pragma unroll
      for (int rt = 0; rt < 2; ++rt) {
        acc1[rt][ct] = __builtin_amdgcn_mfma_f32_16x16x32_f16(ah[rt], bh, acc1[rt][ct], 0, 0, 0);
        acc2[rt][ct] = __builtin_amdgcn_mfma_f32_16x16x32_f16(ah[rt], bl, acc2[rt][ct], 0, 0, 0);
        acc2[rt][ct] = __builtin_amdgcn_mfma_f32_16x16x32_f16(al[rt], bh, acc2[rt][ct], 0, 0, 0);
      }
    }
    asm volatile("" ::: "memory");
    __builtin_amdgcn_s_barrier();  // protect buffers from next-next stage
    asm volatile("" ::: "memory");
  }

  const float S = 1.0f / 2048.0f;
  float* aout = act + ((size_t)blockIdx.x * 4 + w) * 4096 + (size_t)lane * 4;
#pragma unroll
  for (int rt = 0; rt < 2; ++rt)
#pragma unroll
    for (int ct = 0; ct < 8; ++ct) {
      int col = ct * 16 + m;
      float bias = b_in0[col] + b_in1[col];
      floatx4 v;
#pragma unroll
      for (int reg = 0; reg < 4; ++reg)
        v[reg] = acc1[rt][ct][reg] + acc2[rt][ct][reg] * S + bias;
      *reinterpret_cast<floatx4*>(aout + (rt * 8 + ct) * 256) = v;
    }
}

// ---------------------------------------------------------------------------
// K2: resnet (2 blocks of 2 GEMMs + residual) + angle projection, all in
// f16x2 split MFMA. Reads act in k1's fragment-native float4 layout.
// Writes unnorm to d_out.
// ---------------------------------------------------------------------------
__global__ __launch_bounds__(256) void k2_resnet(
    const float* __restrict__ act,
    const unsigned short* __restrict__ wrtH, const unsigned short* __restrict__ wrtL,
    const float* __restrict__ br1, const float* __restrict__ br2,
    const unsigned short* __restrict__ angtH, const unsigned short* __restrict__ angtL,
    const float* __restrict__ b_ang, float* __restrict__ out_unnorm) {
  __shared__ unsigned short XbH[128 * 136], XbL[128 * 136];
  __shared__ unsigned short WbH[128 * 40], WbL[128 * 40];
  const int tid = threadIdx.x;
  const int lane = tid & 63, w = tid >> 6;
  const int q = lane >> 4, m = lane & 15;
  const int row0 = blockIdx.x * 128;
  const float S = 1.0f / 2048.0f;

  floatx4 cur[2][8];
  const float* ain = act + ((size_t)blockIdx.x * 4 + w) * 4096 + (size_t)lane * 4;
#pragma unroll
  for (int rt = 0; rt < 2; ++rt)
#pragma unroll
    for (int ct = 0; ct < 8; ++ct) {
      floatx4 v = *reinterpret_cast<const floatx4*>(ain + (rt * 8 + ct) * 256);
      cur[rt][ct] = v;
      int col = ct * 16 + m;
#pragma unroll
      for (int reg = 0; reg < 4; ++reg) {
        int rl = w * 32 + rt * 16 + q * 4 + reg;
        f2h2(fmaxf(v[reg], 0.f), XbH[rl * 136 + col], XbL[rl * 136 + col]);
      }
    }

  auto gemm = [&](const unsigned short* __restrict__ WH,
                  const unsigned short* __restrict__ WL,
                  floatx4 a1[2][8], floatx4 a2[2][8]) {
    for (int s = 0; s < 4; ++s) {
      __syncthreads();
#pragma unroll
      for (int r = 0; r < 2; ++r) {
        int c = tid + 256 * r;
        int nr = c >> 2, k8 = (c & 3) << 3;
        *reinterpret_cast<uint4*>(&WbH[nr * 40 + k8]) =
            *reinterpret_cast<const uint4*>(WH + nr * 128 + s * 32 + k8);
        *reinterpret_cast<uint4*>(&WbL[nr * 40 + k8]) =
            *reinterpret_cast<const uint4*>(WL + nr * 128 + s * 32 + k8);
      }
      __syncthreads();
      f16x8 ah[2], al[2];
#pragma unroll
      for (int rt = 0; rt < 2; ++rt) {
        ah[rt] = *reinterpret_cast<const f16x8*>(&XbH[(w * 32 + rt * 16 + m) * 136 + s * 32 + q * 8]);
        al[rt] = *reinterpret_cast<const f16x8*>(&XbL[(w * 32 + rt * 16 + m) * 136 + s * 32 + q * 8]);
      }
#pragma unroll
      for (int ct = 0; ct < 8; ++ct) {
        f16x8 bh = *reinterpret_cast<const f16x8*>(&WbH[(ct * 16 + m) * 40 + q * 8]);
        f16x8 bl = *reinterpret_cast<const f16x8*>(&WbL[(ct * 16 + m) * 40 + q * 8]);
#pragma unroll
        for (int rt = 0; rt < 2; ++rt) {
          a1[rt][ct] = __builtin_amdgcn_mfma_f32_16x16x32_f16(ah[rt], bh, a1[rt][ct], 0, 0, 0);
          a2[rt][ct] = __builtin_amdgcn_mfma_f32_16x16x32_f16(ah[rt], bl, a2[rt][ct], 0, 0, 0);
          a2[rt][ct] = __builtin_amdgcn_mfma_f32_16x16x32_f16(al[rt], bh, a2[rt][ct], 0, 0, 0);
        }
      }
    }
  };

  for (int i = 0; i < 2; ++i) {
    // t = relu(cur) @ Wr1[i] + br1[i]
    floatx4 a1[2][8], a2[2][8];
#pragma unroll
    for (int rt = 0; rt < 2; ++rt)
#pragma unroll
      for (int ct = 0; ct < 8; ++ct) {
        a1[rt][ct] = (floatx4){0.f, 0.f, 0.f, 0.f};
        a2[rt][ct] = (floatx4){0.f, 0.f, 0.f, 0.f};
      }
    gemm(wrtH + (size_t)(i * 2 + 0) * 16384, wrtL + (size_t)(i * 2 + 0) * 16384, a1, a2);
    __syncthreads();  // all waves done reading Xb
#pragma unroll
    for (int rt = 0; rt < 2; ++rt)
#pragma unroll
      for (int ct = 0; ct < 8; ++ct) {
        int col = ct * 16 + m;
        float b = br1[i * 128 + col];
#pragma unroll
        for (int reg = 0; reg < 4; ++reg) {
          int rl = w * 32 + rt * 16 + q * 4 + reg;
          float v = a1[rt][ct][reg] + a2[rt][ct][reg] * S + b;
          f2h2(fmaxf(v, 0.f), XbH[rl * 136 + col], XbL[rl * 136 + col]);
        }
      }
    // cur = relu(t) @ Wr2[i] + br2[i] + cur  (residual folded into acc1 init)
    floatx4 c1[2][8], c2[2][8];
#pragma unroll
    for (int rt = 0; rt < 2; ++rt)
#pragma unroll
      for (int ct = 0; ct < 8; ++ct) {
        c1[rt][ct] = cur[rt][ct];
        c2[rt][ct] = (floatx4){0.f, 0.f, 0.f, 0.f};
      }
    gemm(wrtH + (size_t)(i * 2 + 1) * 16384, wrtL + (size_t)(i * 2 + 1) * 16384, c1, c2);
    __syncthreads();
#pragma unroll
    for (int rt = 0; rt < 2; ++rt)
#pragma unroll
      for (int ct = 0; ct < 8; ++ct) {
        int col = ct * 16 + m;
        float b = br2[i * 128 + col];
#pragma unroll
        for (int reg = 0; reg < 4; ++reg) {
          int rl = w * 32 + rt * 16 + q * 4 + reg;
          float v = c1[rt][ct][reg] + c2[rt][ct][reg] * S + b;
          cur[rt][ct][reg] = v;
          f2h2(fmaxf(v, 0.f), XbH[rl * 136 + col], XbL[rl * 136 + col]);
        }
      }
  }

  // unnorm = relu(act) @ w_ang + b_ang  (cols padded 14->16)
  floatx4 A1[2], A2[2];
  A1[0] = (floatx4){0.f, 0.f, 0.f, 0.f}; A1[1] = A1[0];
  A2[0] = A1[0]; A2[1] = A1[0];
  for (int s = 0; s < 4; ++s) {
    __syncthreads();
    if (tid < 64) {
      int nr = tid >> 2, k8 = (tid & 3) << 3;
      *reinterpret_cast<uint4*>(&WbH[nr * 40 + k8]) =
          *reinterpret_cast<const uint4*>(angtH + nr * 128 + s * 32 + k8);
      *reinterpret_cast<uint4*>(&WbL[nr * 40 + k8]) =
          *reinterpret_cast<const uint4*>(angtL + nr * 128 + s * 32 + k8);
    }
    __syncthreads();
    f16x8 bh = *reinterpret_cast<const f16x8*>(&WbH[m * 40 + q * 8]);
    f16x8 bl = *reinterpret_cast<const f16x8*>(&WbL[m * 40 + q * 8]);
#pragma unroll
    for (int rt = 0; rt < 2; ++rt) {
      f16x8 ah = *reinterpret_cast<const f16x8*>(&XbH[(w * 32 + rt * 16 + m) * 136 + s * 32 + q * 8]);
      f16x8 al = *reinterpret_cast<const f16x8*>(&XbL[(w * 32 + rt * 16 + m) * 136 + s * 32 + q * 8]);
      A1[rt] = __builtin_amdgcn_mfma_f32_16x16x32_f16(ah, bh, A1[rt], 0, 0, 0);
      A2[rt] = __builtin_amdgcn_mfma_f32_16x16x32_f16(ah, bl, A2[rt], 0, 0, 0);
      A2[rt] = __builtin_amdgcn_mfma_f32_16x16x32_f16(al, bh, A2[rt], 0, 0, 0);
    }
  }
  if (m < 14) {
    float bias = b_ang[m];
#pragma unroll
    for (int rt = 0; rt < 2; ++rt)
#pragma unroll
      for (int reg = 0; reg < 4; ++reg) {
        int row = row0 + w * 32 + rt * 16 + q * 4 + reg;
        out_unnorm[(size_t)row * 14 + m] = A1[rt][reg] + A2[rt][reg] * S + bias;
      }
  }
}

// ---------------------------------------------------------------------------
// K3: per-residue geometry (fp32). 64 threads/block; per-thread frame stash in
// LDS laid out [element][thread] (conflict-free under divergent group gathers).
// ---------------------------------------------------------------------------
__global__ __launch_bounds__(64) void k3_geom(
    const float* __restrict__ affine, const int* __restrict__ aatype,
    const float* __restrict__ dframes, const int* __restrict__ gidx,
    const float* __restrict__ amask, const float* __restrict__ lpos,
    float* __restrict__ out, int n) {
  __shared__ float lds[96 * 64];
  const int tid = threadIdx.x;
  const int r = blockIdx.x * 64 + tid;
  const size_t OFF0 = 0;
  const size_t OFF1 = (size_t)n * 14;
  const size_t OFF2 = (size_t)n * 28;
  const size_t OFF3 = (size_t)n * 70;
  const size_t OFF4 = (size_t)n * 142;

  float ang[14];
  const float* un = out + OFF1 + (size_t)r * 14;
#pragma unroll
  for (int j = 0; j < 7; ++j) {
    float a = un[2 * j], b = un[2 * j + 1];
    float inv = 1.0f / sqrtf(fmaxf(a * a + b * b, 1e-12f));
    ang[2 * j] = a * inv;
    ang[2 * j + 1] = b * inv;
    out[OFF0 + (size_t)r * 14 + 2 * j] = ang[2 * j];
    out[OFF0 + (size_t)r * 14 + 2 * j + 1] = ang[2 * j + 1];
  }

  const float* af = affine + (size_t)r * 7;
  float qw = af[0], qx = af[1], qy = af[2], qz = af[3];
  float qi = 1.0f / sqrtf(fmaxf(qw * qw + qx * qx + qy * qy + qz * qz, 1e-12f));
  qw *= qi; qx *= qi; qy *= qi; qz *= qi;
  float rb[9];
  rb[0] = 1.f - 2.f * (qy * qy + qz * qz);
  rb[1] = 2.f * (qx * qy - qw * qz);
  rb[2] = 2.f * (qx * qz + qw * qy);
  rb[3] = 2.f * (qx * qy + qw * qz);
  rb[4] = 1.f - 2.f * (qx * qx + qz * qz);
  rb[5] = 2.f * (qy * qz - qw * qx);
  rb[6] = 2.f * (qx * qz - qw * qy);
  rb[7] = 2.f * (qy * qz + qw * qx);
  rb[8] = 1.f - 2.f * (qx * qx + qy * qy);
  float tb0 = af[4], tb1 = af[5], tb2 = af[6];

  int aat = aatype[r];
  const float* mb = dframes + (size_t)aat * 128;
  float sa[8], ca[8];
  sa[0] = 0.f; ca[0] = 1.f;
#pragma unroll
  for (int g = 1; g < 8; ++g) { sa[g] = ang[(g - 1) * 2]; ca[g] = ang[(g - 1) * 2 + 1]; }

  float chr[9], cht[3];
#pragma unroll
  for (int g = 0; g < 8; ++g) {
    const float* M = mb + g * 16;
    float c = ca[g], s = sa[g];
    float rf[9], tf[3];
#pragma unroll
    for (int i = 0; i < 3; ++i) {
      float m1 = M[i * 4 + 1], m2 = M[i * 4 + 2];
      rf[i * 3 + 0] = M[i * 4 + 0];
      rf[i * 3 + 1] = m1 * c + m2 * s;
      rf[i * 3 + 2] = m2 * c - m1 * s;
      tf[i] = M[i * 4 + 3];
    }
    float ra[9], ta[3];
    if (g < 5) {
#pragma unroll
      for (int e = 0; e < 9; ++e) ra[e] = rf[e];
      ta[0] = tf[0]; ta[1] = tf[1]; ta[2] = tf[2];
      if (g == 4) {
#pragma unroll
        for (int e = 0; e < 9; ++e) chr[e] = rf[e];
        cht[0] = tf[0]; cht[1] = tf[1]; cht[2] = tf[2];
      }
    } else {
      float nr[9], nt[3];
#pragma unroll
      for (int i = 0; i < 3; ++i) {
#pragma unroll
        for (int j = 0; j < 3; ++j)
          nr[i * 3 + j] = chr[i * 3 + 0] * rf[0 + j] + chr[i * 3 + 1] * rf[3 + j] +
                          chr[i * 3 + 2] * rf[6 + j];
        nt[i] = chr[i * 3 + 0] * tf[0] + chr[i * 3 + 1] * tf[1] +
                chr[i * 3 + 2] * tf[2] + cht[i];
      }
#pragma unroll
      for (int e = 0; e < 9; ++e) { chr[e] = nr[e]; ra[e] = nr[e]; }
      cht[0] = nt[0]; cht[1] = nt[1]; cht[2] = nt[2];
      ta[0] = nt[0]; ta[1] = nt[1]; ta[2] = nt[2];
    }
    float rg[9], tg[3];
#pragma unroll
    for (int i = 0; i < 3; ++i) {
#pragma unroll
      for (int j = 0; j < 3; ++j)
        rg[i * 3 + j] = rb[i * 3 + 0] * ra[0 + j] + rb[i * 3 + 1] * ra[3 + j] +
                        rb[i * 3 + 2] * ra[6 + j];
      tg[i] = rb[i * 3 + 0] * ta[0] + rb[i * 3 + 1] * ta[1] + rb[i * 3 + 2] * ta[2];
    }
    tg[0] += tb0; tg[1] += tb1; tg[2] += tb2;
#pragma unroll
    for (int e = 0; e < 9; ++e) {
      out[OFF3 + (size_t)r * 72 + g * 9 + e] = rg[e];
      lds[(g * 12 + e) * 64 + tid] = rg[e];
    }
#pragma unroll
    for (int i = 0; i < 3; ++i) {
      out[OFF4 + (size_t)r * 24 + g * 3 + i] = tg[i];
      lds[(g * 12 + 9 + i) * 64 + tid] = tg[i];
    }
  }

#pragma unroll
  for (int a = 0; a < 14; ++a) {
    int gi = gidx[aat * 14 + a];
    float mask = amask[aat * 14 + a];
    const float* lp = lpos + (size_t)(aat * 14 + a) * 3;
    float l0 = lp[0], l1 = lp[1], l2 = lp[2];
    int b = gi * 12;
#pragma unroll
    for (int i = 0; i < 3; ++i) {
      float p = lds[(b + i * 3 + 0) * 64 + tid] * l0 +
                lds[(b + i * 3 + 1) * 64 + tid] * l1 +
                lds[(b + i * 3 + 2) * 64 + tid] * l2 + lds[(b + 9 + i) * 64 + tid];
      out[OFF2 + (size_t)r * 42 + a * 3 + i] = p * mask;
    }
  }
}

// ---------------------------------------------------------------------------
extern "C" void kernel_launch(void* const* d_in, const int* in_sizes, int n_in,
                              void* d_out, int out_size, void* d_ws, size_t ws_size,
                              hipStream_t stream) {
  const float* affine = (const float*)d_in[0];
  const float* rep0 = (const float*)d_in[1];
  const float* rep1 = (const float*)d_in[2];
  const int* aatype = (const int*)d_in[3];
  const float* w_in0 = (const float*)d_in[4];
  const float* b_in0 = (const float*)d_in[5];
  const float* w_in1 = (const float*)d_in[6];
  const float* b_in1 = (const float*)d_in[7];
  const float* Wr1 = (const float*)d_in[8];
  const float* br1 = (const float*)d_in[9];
  const float* Wr2 = (const float*)d_in[10];
  const float* br2 = (const float*)d_in[11];
  const float* w_ang = (const float*)d_in[12];
  const float* b_ang = (const float*)d_in[13];
  const float* dframes = (const float*)d_in[14];
  const int* gidx = (const int*)d_in[15];
  const float* amask = (const float*)d_in[16];
  const float* lpos = (const float*)d_in[17];
  float* out = (float*)d_out;

  const int n = in_sizes[0] / 7;  // N_RES

  char* ws = (char*)d_ws;
  unsigned short* btH = (unsigned short*)ws;      // 98304
  unsigned short* btL = btH + 98304;              // 98304
  unsigned short* wrtH = btL + 98304;             // 65536
  unsigned short* wrtL = wrtH + 65536;            // 65536
  unsigned short* angtH = wrtL + 65536;           // 2048
  unsigned short* angtL = angtH + 2048;           // 2048
  size_t w_bytes = (size_t)(2 * (98304 + 65536 + 2048)) * sizeof(unsigned short);
  size_t act_off = (w_bytes + 255) & ~(size_t)255;
  float* act;
  if (ws_size >= act_off + (size_t)n * 128 * sizeof(float)) {
    act = (float*)(ws + act_off);
  } else {
    // overlay act on d_out's pos/rot_g/trans_g region (138 floats/res >= 128);
    // K3 overwrites it only after K2 has consumed act.
    act = out + (size_t)n * 28;
  }

  k0_convert<<<384, 256, 0, stream>>>(w_in0, w_in1, Wr1, Wr2, w_ang,
                                      btH, btL, wrtH, wrtL, angtH, angtL);
  k1_gemm_in<<<n / 128, 256, 0, stream>>>(rep0, rep1, b_in0, b_in1, btH, btL, act);
  k2_resnet<<<n / 128, 256, 0, stream>>>(act, wrtH, wrtL, br1, br2, angtH, angtL,
                                         b_ang, out + (size_t)n * 14);
  k3_geom<<<n / 64, 64, 0, stream>>>(affine, aatype, dframes, gidx, amask, lpos,
                                     out, n);
}

// Round 2
// 626.740 us; speedup vs baseline: 1.0854x; 1.0790x over previous
//
#include <hip/hip_runtime.h>
#include <stdint.h>

typedef _Float16 f16x8 __attribute__((ext_vector_type(8)));
typedef float floatx4 __attribute__((ext_vector_type(4)));

// Split fp32 into f16 hi + f16 lo, lo pre-scaled by 2048 (2^11) so it stays in
// the f16 normal range (MFMA may flush f16 denormals). x ~= hi + lo/2048.
__device__ __forceinline__ void f2h2(float x, unsigned short& hi, unsigned short& lo) {
  _Float16 h = (_Float16)x;
  float r = (x - (float)h) * 2048.0f;
  _Float16 l = (_Float16)r;
  union { _Float16 f; unsigned short u; } a, b;
  a.f = h; b.f = l;
  hi = a.u; lo = b.u;
}

// Async global->LDS 16B copy. LDS dest is wave-uniform base + lane*16 (HW);
// global source is per-lane.
__device__ __forceinline__ void async_copy16(void* lds, const void* gsrc) {
  __builtin_amdgcn_global_load_lds(
      (const __attribute__((address_space(1))) unsigned int*)gsrc,
      (__attribute__((address_space(3))) unsigned int*)lds, 16, 0, 0);
}

// ---------------------------------------------------------------------------
// K0: weight conversion to f16 hi/lo pairs.
//   bt  : fragment-major layout for k1's direct register loads:
//         btH[((s*8+ct)*64+lane)*8+e] = H(B[n=ct*16+(lane&15)][k=s*32+(lane>>4)*8+e])
//         (s=0..23 K-steps of 32; k<384 -> w_in0, k>=384 -> w_in1)
//   wrt : unchanged [128 n][128 k], 4 mats Wr1[0],Wr2[0],Wr1[1],Wr2[1]
//   angt: unchanged [16 n][128 k] (n>=14 zero-padded)
// ---------------------------------------------------------------------------
__global__ __launch_bounds__(256) void k0_convert(
    const float* __restrict__ w_in0, const float* __restrict__ w_in1,
    const float* __restrict__ Wr1, const float* __restrict__ Wr2,
    const float* __restrict__ w_ang,
    unsigned short* __restrict__ btH, unsigned short* __restrict__ btL,
    unsigned short* __restrict__ wrtH, unsigned short* __restrict__ wrtL,
    unsigned short* __restrict__ angtH, unsigned short* __restrict__ angtL) {
  int e = blockIdx.x * 256 + threadIdx.x;
  if (e < 24 * 4096) {  // 98304: fragment-major bt
    int s = e >> 12, rem = e & 4095;
    int ct = rem >> 9, lane = (rem >> 3) & 63, el = rem & 7;
    int n = ct * 16 + (lane & 15);
    int k = s * 32 + ((lane >> 4) << 3) + el;
    float v = (k < 384) ? w_in0[k * 128 + n] : w_in1[(k - 384) * 128 + n];
    f2h2(v, btH[e], btL[e]);
  }
  if (e < 4 * 128 * 128) {
    int mi = e / 16384, rem = e % 16384;
    int n = rem / 128, k = rem % 128;
    int blk = mi >> 1, which = mi & 1;
    const float* W = which ? Wr2 : Wr1;
    f2h2(W[blk * 16384 + k * 128 + n], wrtH[e], wrtL[e]);
  }
  if (e < 16 * 128) {
    int n = e / 128, k = e % 128;
    float v = (n < 14) ? w_ang[k * 14 + n] : 0.0f;
    f2h2(v, angtH[e], angtL[e]);
  }
}

// ---------------------------------------------------------------------------
// K1 v2: act[N,128] = relu(rep0)@w_in0 + relu(rep1)@w_in1 + (b_in0+b_in1)
// DRAM-page-friendly design: 32-row blocks; A staged as CONTIGUOUS 768-B
// row-segments (4 phases: rep0 k[0:192), rep0 k[192:384), rep1 ditto), each
// phase tile 32x192 fp32 = 24 KB, double-buffered (48 KB LDS, 3 blocks/CU).
// A LDS uses byte XOR-swizzle ((row&7)<<4) applied on the pre-permuted GLOBAL
// source (linear LDS dest, rule both-sides-or-neither) so the 16-row-strided
// ds_read_b128 fragment reads are conflict-free.
// B fragments load directly L2->VGPR (fragment-major bt layout is coalesced
// 16 B/lane) with a 1-step register prefetch; no B LDS, no per-step barriers.
// act output: fragment-native flat layout (identical to previous round):
//   act[(g32*16 + rt*8 + ct)*256 + lane*4 + reg], g32 = global 32-row group.
// ---------------------------------------------------------------------------
__global__ __launch_bounds__(256, 3) void k1_gemm_in(
    const float* __restrict__ rep0, const float* __restrict__ rep1,
    const float* __restrict__ b_in0, const float* __restrict__ b_in1,
    const unsigned short* __restrict__ btH, const unsigned short* __restrict__ btL,
    float* __restrict__ act) {
  __shared__ float A[2][6144];  // 2 x 24 KB
  const int tid = threadIdx.x;
  const int lane = tid & 63, w = tid >> 6;
  const int q = lane >> 4, m = lane & 15;
  const int row0 = blockIdx.x * 32;

  // Precompute per-lane prefetch source offsets (floats within a 32x192 tile
  // region of rep, before +koff) and wave-uniform LDS byte dests.
  // slot sb = (w*6+i)*1024 + lane*16 bytes; row = sb/768; col = sb%768;
  // source col is pre-XOR'd so that LDS stays linear while reads swizzle.
  int srcf[6], dstb[6];
#pragma unroll
  for (int i = 0; i < 6; ++i) {
    int sb = (w * 6 + i) * 1024 + lane * 16;
    int row = sb / 768;
    int colb = sb - row * 768;
    int cswz = colb ^ ((row & 7) << 4);
    srcf[i] = row * 384 + (cswz >> 2);
    dstb[i] = (w * 6 + i) * 1024;
  }

  floatx4 acc1[2][2], acc2[2][2];
#pragma unroll
  for (int rt = 0; rt < 2; ++rt)
#pragma unroll
    for (int j = 0; j < 2; ++j) {
      acc1[rt][j] = (floatx4){0.f, 0.f, 0.f, 0.f};
      acc2[rt][j] = (floatx4){0.f, 0.f, 0.f, 0.f};
    }

  auto stage = [&](int buf, int p) {
    const float* __restrict__ rp = (p < 2) ? rep0 : rep1;
    const float* src = rp + (size_t)row0 * 384 + (p & 1) * 192;
    char* db = (char*)&A[buf][0];
#pragma unroll
    for (int i = 0; i < 6; ++i) async_copy16(db + dstb[i], src + srcf[i]);
  };

  auto loadB = [&](int sg, f16x8* bh, f16x8* bl) {
#pragma unroll
    for (int j = 0; j < 2; ++j) {
      int ct = 2 * w + j;
      size_t off = ((size_t)(sg * 8 + ct) * 64 + lane) * 8;
      bh[j] = *reinterpret_cast<const f16x8*>(btH + off);
      bl[j] = *reinterpret_cast<const f16x8*>(btL + off);
    }
  };

  f16x8 bhc[2], blc[2];
  loadB(0, bhc, blc);
  stage(0, 0);

  for (int p = 0; p < 4; ++p) {
    // barrier 1: everyone done reading the buffer the next prefetch overwrites
    __builtin_amdgcn_s_barrier();
    if (p < 3) stage((p + 1) & 1, p + 1);
    asm volatile("" ::: "memory");
    if (p < 3)
      asm volatile("s_waitcnt vmcnt(6)" ::: "memory");  // phase-p tile done; 6 newest stay in flight
    else
      asm volatile("s_waitcnt vmcnt(0)" ::: "memory");
    __builtin_amdgcn_s_barrier();  // all waves' tile-p writes visible
    asm volatile("" ::: "memory");

    const float* Ab = &A[p & 1][0];
#pragma unroll
    for (int sl = 0; sl < 6; ++sl) {
      int sg = p * 6 + sl;
      // prefetch next step's B fragments into registers
      f16x8 bhn[2], bln[2];
      loadB(sg < 23 ? sg + 1 : 23, bhn, bln);

      // A fragments: swizzled LDS read, relu + hi/lo split in registers
      f16x8 ah[2], al[2];
#pragma unroll
      for (int rt = 0; rt < 2; ++rt) {
        int row = rt * 16 + m;
        int boff = (row * 768 + sl * 128 + q * 32) ^ ((row & 7) << 4);
        float4 x0 = *reinterpret_cast<const float4*>((const char*)Ab + boff);
        float4 x1 = *reinterpret_cast<const float4*>((const char*)Ab + (boff ^ 16));
        float xs[8] = {x0.x, x0.y, x0.z, x0.w, x1.x, x1.y, x1.z, x1.w};
#pragma unroll
        for (int e = 0; e < 8; ++e) {
          float x = fmaxf(xs[e], 0.f);
          _Float16 hh = (_Float16)x;
          ah[rt][e] = hh;
          al[rt][e] = (_Float16)((x - (float)hh) * 2048.0f);
        }
      }
#pragma unroll
      for (int j = 0; j < 2; ++j)
#pragma unroll
        for (int rt = 0; rt < 2; ++rt) {
          acc1[rt][j] = __builtin_amdgcn_mfma_f32_16x16x32_f16(ah[rt], bhc[j], acc1[rt][j], 0, 0, 0);
          acc2[rt][j] = __builtin_amdgcn_mfma_f32_16x16x32_f16(ah[rt], blc[j], acc2[rt][j], 0, 0, 0);
          acc2[rt][j] = __builtin_amdgcn_mfma_f32_16x16x32_f16(al[rt], bhc[j], acc2[rt][j], 0, 0, 0);
        }
      bhc[0] = bhn[0]; bhc[1] = bhn[1];
      blc[0] = bln[0]; blc[1] = bln[1];
    }
  }

  const float S = 1.0f / 2048.0f;
#pragma unroll
  for (int rt = 0; rt < 2; ++rt)
#pragma unroll
    for (int j = 0; j < 2; ++j) {
      int ct = 2 * w + j;
      int col = ct * 16 + m;
      float bias = b_in0[col] + b_in1[col];
      floatx4 v;
#pragma unroll
      for (int reg = 0; reg < 4; ++reg)
        v[reg] = acc1[rt][j][reg] + acc2[rt][j][reg] * S + bias;
      *reinterpret_cast<floatx4*>(
          act + (((size_t)blockIdx.x * 2 + rt) * 8 + ct) * 256 + lane * 4) = v;
    }
}

// ---------------------------------------------------------------------------
// K2: resnet (2 blocks of 2 GEMMs + residual) + angle projection, all in
// f16x2 split MFMA. Reads act in k1's fragment-native float4 layout.
// Writes unnorm to d_out.
// ---------------------------------------------------------------------------
__global__ __launch_bounds__(256) void k2_resnet(
    const float* __restrict__ act,
    const unsigned short* __restrict__ wrtH, const unsigned short* __restrict__ wrtL,
    const float* __restrict__ br1, const float* __restrict__ br2,
    const unsigned short* __restrict__ angtH, const unsigned short* __restrict__ angtL,
    const float* __restrict__ b_ang, float* __restrict__ out_unnorm) {
  __shared__ unsigned short XbH[128 * 136], XbL[128 * 136];
  __shared__ unsigned short WbH[128 * 40], WbL[128 * 40];
  const int tid = threadIdx.x;
  const int lane = tid & 63, w = tid >> 6;
  const int q = lane >> 4, m = lane & 15;
  const int row0 = blockIdx.x * 128;
  const float S = 1.0f / 2048.0f;

  floatx4 cur[2][8];
  const float* ain = act + ((size_t)blockIdx.x * 4 + w) * 4096 + (size_t)lane * 4;
#pragma unroll
  for (int rt = 0; rt < 2; ++rt)
#pragma unroll
    for (int ct = 0; ct < 8; ++ct) {
      floatx4 v = *reinterpret_cast<const floatx4*>(ain + (rt * 8 + ct) * 256);
      cur[rt][ct] = v;
      int col = ct * 16 + m;
#pragma unroll
      for (int reg = 0; reg < 4; ++reg) {
        int rl = w * 32 + rt * 16 + q * 4 + reg;
        f2h2(fmaxf(v[reg], 0.f), XbH[rl * 136 + col], XbL[rl * 136 + col]);
      }
    }

  auto gemm = [&](const unsigned short* __restrict__ WH,
                  const unsigned short* __restrict__ WL,
                  floatx4 a1[2][8], floatx4 a2[2][8]) {
    for (int s = 0; s < 4; ++s) {
      __syncthreads();
#pragma unroll
      for (int r = 0; r < 2; ++r) {
        int c = tid + 256 * r;
        int nr = c >> 2, k8 = (c & 3) << 3;
        *reinterpret_cast<uint4*>(&WbH[nr * 40 + k8]) =
            *reinterpret_cast<const uint4*>(WH + nr * 128 + s * 32 + k8);
        *reinterpret_cast<uint4*>(&WbL[nr * 40 + k8]) =
            *reinterpret_cast<const uint4*>(WL + nr * 128 + s * 32 + k8);
      }
      __syncthreads();
      f16x8 ah[2], al[2];
#pragma unroll
      for (int rt = 0; rt < 2; ++rt) {
        ah[rt] = *reinterpret_cast<const f16x8*>(&XbH[(w * 32 + rt * 16 + m) * 136 + s * 32 + q * 8]);
        al[rt] = *reinterpret_cast<const f16x8*>(&XbL[(w * 32 + rt * 16 + m) * 136 + s * 32 + q * 8]);
      }
#pragma unroll
      for (int ct = 0; ct < 8; ++ct) {
        f16x8 bh = *reinterpret_cast<const f16x8*>(&WbH[(ct * 16 + m) * 40 + q * 8]);
        f16x8 bl = *reinterpret_cast<const f16x8*>(&WbL[(ct * 16 + m) * 40 + q * 8]);
#pragma unroll
        for (int rt = 0; rt < 2; ++rt) {
          a1[rt][ct] = __builtin_amdgcn_mfma_f32_16x16x32_f16(ah[rt], bh, a1[rt][ct], 0, 0, 0);
          a2[rt][ct] = __builtin_amdgcn_mfma_f32_16x16x32_f16(ah[rt], bl, a2[rt][ct], 0, 0, 0);
          a2[rt][ct] = __builtin_amdgcn_mfma_f32_16x16x32_f16(al[rt], bh, a2[rt][ct], 0, 0, 0);
        }
      }
    }
  };

  for (int i = 0; i < 2; ++i) {
    floatx4 a1[2][8], a2[2][8];
#pragma unroll
    for (int rt = 0; rt < 2; ++rt)
#pragma unroll
      for (int ct = 0; ct < 8; ++ct) {
        a1[rt][ct] = (floatx4){0.f, 0.f, 0.f, 0.f};
        a2[rt][ct] = (floatx4){0.f, 0.f, 0.f, 0.f};
      }
    gemm(wrtH + (size_t)(i * 2 + 0) * 16384, wrtL + (size_t)(i * 2 + 0) * 16384, a1, a2);
    __syncthreads();
#pragma unroll
    for (int rt = 0; rt < 2; ++rt)
#pragma unroll
      for (int ct = 0; ct < 8; ++ct) {
        int col = ct * 16 + m;
        float b = br1[i * 128 + col];
#pragma unroll
        for (int reg = 0; reg < 4; ++reg) {
          int rl = w * 32 + rt * 16 + q * 4 + reg;
          float v = a1[rt][ct][reg] + a2[rt][ct][reg] * S + b;
          f2h2(fmaxf(v, 0.f), XbH[rl * 136 + col], XbL[rl * 136 + col]);
        }
      }
    floatx4 c1[2][8], c2[2][8];
#pragma unroll
    for (int rt = 0; rt < 2; ++rt)
#pragma unroll
      for (int ct = 0; ct < 8; ++ct) {
        c1[rt][ct] = cur[rt][ct];
        c2[rt][ct] = (floatx4){0.f, 0.f, 0.f, 0.f};
      }
    gemm(wrtH + (size_t)(i * 2 + 1) * 16384, wrtL + (size_t)(i * 2 + 1) * 16384, c1, c2);
    __syncthreads();
#pragma unroll
    for (int rt = 0; rt < 2; ++rt)
#pragma unroll
      for (int ct = 0; ct < 8; ++ct) {
        int col = ct * 16 + m;
        float b = br2[i * 128 + col];
#pragma unroll
        for (int reg = 0; reg < 4; ++reg) {
          int rl = w * 32 + rt * 16 + q * 4 + reg;
          float v = c1[rt][ct][reg] + c2[rt][ct][reg] * S + b;
          cur[rt][ct][reg] = v;
          f2h2(fmaxf(v, 0.f), XbH[rl * 136 + col], XbL[rl * 136 + col]);
        }
      }
  }

  floatx4 A1[2], A2[2];
  A1[0] = (floatx4){0.f, 0.f, 0.f, 0.f}; A1[1] = A1[0];
  A2[0] = A1[0]; A2[1] = A1[0];
  for (int s = 0; s < 4; ++s) {
    __syncthreads();
    if (tid < 64) {
      int nr = tid >> 2, k8 = (tid & 3) << 3;
      *reinterpret_cast<uint4*>(&WbH[nr * 40 + k8]) =
          *reinterpret_cast<const uint4*>(angtH + nr * 128 + s * 32 + k8);
      *reinterpret_cast<uint4*>(&WbL[nr * 40 + k8]) =
          *reinterpret_cast<const uint4*>(angtL + nr * 128 + s * 32 + k8);
    }
    __syncthreads();
    f16x8 bh = *reinterpret_cast<const f16x8*>(&WbH[m * 40 + q * 8]);
    f16x8 bl = *reinterpret_cast<const f16x8*>(&WbL[m * 40 + q * 8]);
#pragma unroll
    for (int rt = 0; rt < 2; ++rt) {
      f16x8 ah = *reinterpret_cast<const f16x8*>(&XbH[(w * 32 + rt * 16 + m) * 136 + s * 32 + q * 8]);
      f16x8 al = *reinterpret_cast<const f16x8*>(&XbL[(w * 32 + rt * 16 + m) * 136 + s * 32 + q * 8]);
      A1[rt] = __builtin_amdgcn_mfma_f32_16x16x32_f16(ah, bh, A1[rt], 0, 0, 0);
      A2[rt] = __builtin_amdgcn_mfma_f32_16x16x32_f16(ah, bl, A2[rt], 0, 0, 0);
      A2[rt] = __builtin_amdgcn_mfma_f32_16x16x32_f16(al, bh, A2[rt], 0, 0, 0);
    }
  }
  if (m < 14) {
    float bias = b_ang[m];
#pragma unroll
    for (int rt = 0; rt < 2; ++rt)
#pragma unroll
      for (int reg = 0; reg < 4; ++reg) {
        int row = row0 + w * 32 + rt * 16 + q * 4 + reg;
        out_unnorm[(size_t)row * 14 + m] = A1[rt][reg] + A2[rt][reg] * S + bias;
      }
  }
}

// ---------------------------------------------------------------------------
// K3 v2: per-residue geometry (fp32), 64 threads/block, fully COALESCED I/O.
// All outputs routed through a padded per-thread-column LDS stash
// (stride 65 breaks the row*64 bank alignment), then written as contiguous
// float4 streams. unnorm is staged in coalesced float4s the same way.
// Stash rows: [0,96) rot/trans (g*12+e, g*12+9+i); [96,138) pos; [138,152) ang.
// ---------------------------------------------------------------------------
__global__ __launch_bounds__(64) void k3_geom(
    const float* __restrict__ affine, const int* __restrict__ aatype,
    const float* __restrict__ dframes, const int* __restrict__ gidx,
    const float* __restrict__ amask, const float* __restrict__ lpos,
    float* __restrict__ out, int n) {
  __shared__ float lds[152 * 65];
  const int tid = threadIdx.x;
  const int rblk = blockIdx.x * 64;
  const int r = rblk + tid;
  const size_t OFF0 = 0;
  const size_t OFF1 = (size_t)n * 14;
  const size_t OFF2 = (size_t)n * 28;
  const size_t OFF3 = (size_t)n * 70;
  const size_t OFF4 = (size_t)n * 142;

  // Stage unnorm (64 res x 14) coalesced: 224 float4s.
  {
    const float* unb = out + OFF1 + (size_t)rblk * 14;
#pragma unroll
    for (int it = 0; it < 4; ++it) {
      int f4 = it * 64 + tid;
      if (f4 < 224) {
        float4 v = *reinterpret_cast<const float4*>(unb + f4 * 4);
#pragma unroll
        for (int jj = 0; jj < 4; ++jj) {
          int j = f4 * 4 + jj;
          int rl = j / 14, c = j - rl * 14;
          lds[(138 + c) * 65 + rl] = ((const float*)&v)[jj];
        }
      }
    }
  }
  __syncthreads();

  float ang[14];
#pragma unroll
  for (int j = 0; j < 7; ++j) {
    float a = lds[(138 + 2 * j) * 65 + tid];
    float b = lds[(138 + 2 * j + 1) * 65 + tid];
    float inv = 1.0f / sqrtf(fmaxf(a * a + b * b, 1e-12f));
    ang[2 * j] = a * inv;
    ang[2 * j + 1] = b * inv;
  }
  __syncthreads();
#pragma unroll
  for (int j = 0; j < 14; ++j) lds[(138 + j) * 65 + tid] = ang[j];

  const float* af = affine + (size_t)r * 7;
  float qw = af[0], qx = af[1], qy = af[2], qz = af[3];
  float qi = 1.0f / sqrtf(fmaxf(qw * qw + qx * qx + qy * qy + qz * qz, 1e-12f));
  qw *= qi; qx *= qi; qy *= qi; qz *= qi;
  float rb[9];
  rb[0] = 1.f - 2.f * (qy * qy + qz * qz);
  rb[1] = 2.f * (qx * qy - qw * qz);
  rb[2] = 2.f * (qx * qz + qw * qy);
  rb[3] = 2.f * (qx * qy + qw * qz);
  rb[4] = 1.f - 2.f * (qx * qx + qz * qz);
  rb[5] = 2.f * (qy * qz - qw * qx);
  rb[6] = 2.f * (qx * qz - qw * qy);
  rb[7] = 2.f * (qy * qz + qw * qx);
  rb[8] = 1.f - 2.f * (qx * qx + qy * qy);
  float tb0 = af[4], tb1 = af[5], tb2 = af[6];

  int aat = aatype[r];
  const float* mb = dframes + (size_t)aat * 128;
  float sa[8], ca[8];
  sa[0] = 0.f; ca[0] = 1.f;
#pragma unroll
  for (int g = 1; g < 8; ++g) { sa[g] = ang[(g - 1) * 2]; ca[g] = ang[(g - 1) * 2 + 1]; }

  float chr[9], cht[3];
#pragma unroll
  for (int g = 0; g < 8; ++g) {
    const float* M = mb + g * 16;
    float c = ca[g], s = sa[g];
    float rf[9], tf[3];
#pragma unroll
    for (int i = 0; i < 3; ++i) {
      float m1 = M[i * 4 + 1], m2 = M[i * 4 + 2];
      rf[i * 3 + 0] = M[i * 4 + 0];
      rf[i * 3 + 1] = m1 * c + m2 * s;
      rf[i * 3 + 2] = m2 * c - m1 * s;
      tf[i] = M[i * 4 + 3];
    }
    float ra[9], ta[3];
    if (g < 5) {
#pragma unroll
      for (int e = 0; e < 9; ++e) ra[e] = rf[e];
      ta[0] = tf[0]; ta[1] = tf[1]; ta[2] = tf[2];
      if (g == 4) {
#pragma unroll
        for (int e = 0; e < 9; ++e) chr[e] = rf[e];
        cht[0] = tf[0]; cht[1] = tf[1]; cht[2] = tf[2];
      }
    } else {
      float nr[9], nt[3];
#pragma unroll
      for (int i = 0; i < 3; ++i) {
#pragma unroll
        for (int j = 0; j < 3; ++j)
          nr[i * 3 + j] = chr[i * 3 + 0] * rf[0 + j] + chr[i * 3 + 1] * rf[3 + j] +
                          chr[i * 3 + 2] * rf[6 + j];
        nt[i] = chr[i * 3 + 0] * tf[0] + chr[i * 3 + 1] * tf[1] +
                chr[i * 3 + 2] * tf[2] + cht[i];
      }
#pragma unroll
      for (int e = 0; e < 9; ++e) { chr[e] = nr[e]; ra[e] = nr[e]; }
      cht[0] = nt[0]; cht[1] = nt[1]; cht[2] = nt[2];
      ta[0] = nt[0]; ta[1] = nt[1]; ta[2] = nt[2];
    }
    float rg[9], tg[3];
#pragma unroll
    for (int i = 0; i < 3; ++i) {
#pragma unroll
      for (int j = 0; j < 3; ++j)
        rg[i * 3 + j] = rb[i * 3 + 0] * ra[0 + j] + rb[i * 3 + 1] * ra[3 + j] +
                        rb[i * 3 + 2] * ra[6 + j];
      tg[i] = rb[i * 3 + 0] * ta[0] + rb[i * 3 + 1] * ta[1] + rb[i * 3 + 2] * ta[2];
    }
    tg[0] += tb0; tg[1] += tb1; tg[2] += tb2;
#pragma unroll
    for (int e = 0; e < 9; ++e) lds[(g * 12 + e) * 65 + tid] = rg[e];
#pragma unroll
    for (int i = 0; i < 3; ++i) lds[(g * 12 + 9 + i) * 65 + tid] = tg[i];
  }

#pragma unroll
  for (int a = 0; a < 14; ++a) {
    int gi = gidx[aat * 14 + a];
    float mask = amask[aat * 14 + a];
    const float* lp = lpos + (size_t)(aat * 14 + a) * 3;
    float l0 = lp[0], l1 = lp[1], l2 = lp[2];
    int b = gi * 12;
#pragma unroll
    for (int i = 0; i < 3; ++i) {
      float p = lds[(b + i * 3 + 0) * 65 + tid] * l0 +
                lds[(b + i * 3 + 1) * 65 + tid] * l1 +
                lds[(b + i * 3 + 2) * 65 + tid] * l2 + lds[(b + 9 + i) * 65 + tid];
      lds[(96 + a * 3 + i) * 65 + tid] = p * mask;
    }
  }
  __syncthreads();

  // ---- coalesced write-out phases ----
  // ang: 64x14 = 224 float4
  {
    float* dst = out + OFF0 + (size_t)rblk * 14;
#pragma unroll
    for (int it = 0; it < 4; ++it) {
      int f4 = it * 64 + tid;
      if (f4 < 224) {
        float4 v;
#pragma unroll
        for (int jj = 0; jj < 4; ++jj) {
          int j = f4 * 4 + jj;
          int rl = j / 14, c = j - rl * 14;
          ((float*)&v)[jj] = lds[(138 + c) * 65 + rl];
        }
        *reinterpret_cast<float4*>(dst + f4 * 4) = v;
      }
    }
  }
  // pos: 64x42 = 672 float4
  {
    float* dst = out + OFF2 + (size_t)rblk * 42;
#pragma unroll
    for (int it = 0; it < 11; ++it) {
      int f4 = it * 64 + tid;
      if (f4 < 672) {
        float4 v;
#pragma unroll
        for (int jj = 0; jj < 4; ++jj) {
          int j = f4 * 4 + jj;
          int rl = j / 42, c = j - rl * 42;
          ((float*)&v)[jj] = lds[(96 + c) * 65 + rl];
        }
        *reinterpret_cast<float4*>(dst + f4 * 4) = v;
      }
    }
  }
  // rot: 64x72 = 1152 float4 (18 exact iters; 72 = 18*4 so no residue-crossing)
  {
    float* dst = out + OFF3 + (size_t)rblk * 72;
#pragma unroll
    for (int it = 0; it < 18; ++it) {
      int f4 = it * 64 + tid;
      int rl = f4 / 18;
      int c4 = (f4 - rl * 18) * 4;
      float4 v;
#pragma unroll
      for (int jj = 0; jj < 4; ++jj) {
        int j = c4 + jj;
        int g = j / 9, e = j - g * 9;
        ((float*)&v)[jj] = lds[(g * 12 + e) * 65 + rl];
      }
      *reinterpret_cast<float4*>(dst + f4 * 4) = v;
    }
  }
  // trans: 64x24 = 384 float4 (6 exact iters)
  {
    float* dst = out + OFF4 + (size_t)rblk * 24;
#pragma unroll
    for (int it = 0; it < 6; ++it) {
      int f4 = it * 64 + tid;
      int rl = f4 / 6;
      int c4 = (f4 - rl * 6) * 4;
      float4 v;
#pragma unroll
      for (int jj = 0; jj < 4; ++jj) {
        int j = c4 + jj;
        int g = j / 3, i = j - g * 3;
        ((float*)&v)[jj] = lds[(g * 12 + 9 + i) * 65 + rl];
      }
      *reinterpret_cast<float4*>(dst + f4 * 4) = v;
    }
  }
}

// ---------------------------------------------------------------------------
extern "C" void kernel_launch(void* const* d_in, const int* in_sizes, int n_in,
                              void* d_out, int out_size, void* d_ws, size_t ws_size,
                              hipStream_t stream) {
  const float* affine = (const float*)d_in[0];
  const float* rep0 = (const float*)d_in[1];
  const float* rep1 = (const float*)d_in[2];
  const int* aatype = (const int*)d_in[3];
  const float* w_in0 = (const float*)d_in[4];
  const float* b_in0 = (const float*)d_in[5];
  const float* w_in1 = (const float*)d_in[6];
  const float* b_in1 = (const float*)d_in[7];
  const float* Wr1 = (const float*)d_in[8];
  const float* br1 = (const float*)d_in[9];
  const float* Wr2 = (const float*)d_in[10];
  const float* br2 = (const float*)d_in[11];
  const float* w_ang = (const float*)d_in[12];
  const float* b_ang = (const float*)d_in[13];
  const float* dframes = (const float*)d_in[14];
  const int* gidx = (const int*)d_in[15];
  const float* amask = (const float*)d_in[16];
  const float* lpos = (const float*)d_in[17];
  float* out = (float*)d_out;

  const int n = in_sizes[0] / 7;  // N_RES

  char* ws = (char*)d_ws;
  unsigned short* btH = (unsigned short*)ws;      // 98304
  unsigned short* btL = btH + 98304;              // 98304
  unsigned short* wrtH = btL + 98304;             // 65536
  unsigned short* wrtL = wrtH + 65536;            // 65536
  unsigned short* angtH = wrtL + 65536;           // 2048
  unsigned short* angtL = angtH + 2048;           // 2048
  size_t w_bytes = (size_t)(2 * (98304 + 65536 + 2048)) * sizeof(unsigned short);
  size_t act_off = (w_bytes + 255) & ~(size_t)255;
  float* act;
  if (ws_size >= act_off + (size_t)n * 128 * sizeof(float)) {
    act = (float*)(ws + act_off);
  } else {
    // overlay act on d_out's pos/rot_g/trans_g region (138 floats/res >= 128);
    // K3 overwrites it only after K2 has consumed act.
    act = out + (size_t)n * 28;
  }

  k0_convert<<<384, 256, 0, stream>>>(w_in0, w_in1, Wr1, Wr2, w_ang,
                                      btH, btL, wrtH, wrtL, angtH, angtL);
  k1_gemm_in<<<n / 32, 256, 0, stream>>>(rep0, rep1, b_in0, b_in1, btH, btL, act);
  k2_resnet<<<n / 128, 256, 0, stream>>>(act, wrtH, wrtL, br1, br2, angtH, angtL,
                                         b_ang, out + (size_t)n * 14);
  k3_geom<<<n / 64, 64, 0, stream>>>(affine, aatype, dframes, gidx, amask, lpos,
                                     out, n);
}